// Round 5
// baseline (292.783 us; speedup 1.0000x reference)
//
#include <hip/hip_runtime.h>
#include <hip/hip_bf16.h>
#include <math.h>

// ChordAwareTransformer bf16-MFMA pipeline, round 11 (resubmit — infra failure).
//   Qcat=[pitch_q|harmony_q|voice_q] (d=192) vs Kcat=[k|chord_f|bass_f]
// R11 changes vs R10 (k-split falsified: fewer LDS reads but ALL pipes less
// busy, 90us; R8's 24% idle is overlap-starvation, not LDS BW):
//  * attn reverts to R8 per-wave dataflow (wave owns 16q x full K-tile,
//    wave-private P, no cross-wave reduce) but re-parameterized for 4
//    independent barrier domains per CU: ATQ=64, 4 waves/block, KVBLK=32,
//    64 K-tiles. LDS 36 KB (2x16KB dbuf + 4KB P) -> 4 blocks/CU (144KB),
//    grid 1024 = 256 CUs x 4 resident, zero tail.
//  * Q loaded direct global->VGPR (6x16B/lane, one-time, L2-hit): no Q
//    LDS staging, two fewer barriers.
//  * swizzles: K rows 128B pos=c^(key&7) (attn-proven); V/P rows 64B
//    pos=c^((row>>1)&3) (gemm-proven).
// MFMA layouts (HW-verified, learn_hip m89/m91/m120):
//   A: [m=lane&15][k=quad*8+j]  B: [k=quad*8+j][n=lane&15]
//   C/D: [row=quad*4+reg][col=lane&15]

#define D_    1024
#define H_    16
#define B_    2
#define S_    2048
#define M_    (B_*S_)
#define NCAT_ 5120

#define QSCALE_ (1.44269504f / 24.0f)   // log2e * (1/sqrt(64)) / 3

#if __has_builtin(__builtin_amdgcn_exp2f)
#define EXP2(x) __builtin_amdgcn_exp2f(x)
#else
#define EXP2(x) exp2f(x)
#endif

typedef __attribute__((ext_vector_type(8))) short s16x8;
typedef __attribute__((ext_vector_type(4))) float f32x4;

__device__ __forceinline__ unsigned short f2bf(float f) {
    unsigned u = __builtin_bit_cast(unsigned, f);
    u += 0x7fff + ((u >> 16) & 1);          // RNE
    return (unsigned short)(u >> 16);
}
// packed f32x2 -> bf16x2 (v_cvt_pk_bf16_f32, RNE); low short = a
__device__ __forceinline__ unsigned pk2(float a, float b) {
    __hip_bfloat162 h = __float22bfloat162_rn(float2{a, b});
    unsigned r;
    __builtin_memcpy(&r, &h, 4);
    return r;
}

#define GLDS16(gp, lp) \
    __builtin_amdgcn_global_load_lds((const __attribute__((address_space(1))) void*)(gp), \
                                     (__attribute__((address_space(3))) void*)(lp), 16, 0, 0)

// ---------------------------------------------------------------- prep (fused)
struct PrepArgs {
    const float* x;
    const float* pitch_pc; const float* bass_pc;
    const float* Wc; const float* bc;
    const float* Wb; const float* bb;
    const float* wsrc[6]; unsigned short* wdst[6];
    const float* bsrc[5]; float* bias5;
    unsigned short* xb; unsigned short* cfb; unsigned short* bfb;
};

__global__ __launch_bounds__(256) void prep_kernel(PrepArgs a) {
    __shared__ unsigned short t[64][72];
    int bx = blockIdx.x;
    const int tid = threadIdx.x;

    if (bx < 4096) {                       // ---- cvt_x (fp32 -> bf16)
        int i = (bx * 256 + tid) * 4;
        float4 v = *(const float4*)(a.x + i);
        uint2 o = {pk2(v.x, v.y), pk2(v.z, v.w)};
        *(uint2*)(a.xb + i) = o;
        return;
    }
    bx -= 4096;
    if (bx < 1536) {                       // ---- wtrans (6 weights, 64x64 tiles)
        int z = bx >> 8, rem = bx & 255;
        const float* src = a.wsrc[z];
        unsigned short* dst = a.wdst[z];
        int k0 = (rem >> 4) * 64, n0 = (rem & 15) * 64;
        int r = tid >> 2, c0 = (tid & 3) * 16;
#pragma unroll
        for (int i = 0; i < 4; ++i) {
            float4 v = *(const float4*)(src + (size_t)(k0 + r) * 1024 + n0 + c0 + i * 4);
            ushort4 o = {f2bf(v.x), f2bf(v.y), f2bf(v.z), f2bf(v.w)};
            *(ushort4*)&t[r][c0 + i * 4] = o;
        }
        __syncthreads();
#pragma unroll
        for (int i = 0; i < 4; ++i) {
            ushort4 o = {t[c0 + i*4 + 0][r], t[c0 + i*4 + 1][r],
                         t[c0 + i*4 + 2][r], t[c0 + i*4 + 3][r]};
            *(ushort4*)(dst + (size_t)(n0 + r) * 1024 + k0 + c0 + i * 4) = o;
        }
        return;
    }
    bx -= 1536;
    if (bx < 20) {                         // ---- bpack
        int i = bx * 256 + tid;
        a.bias5[i] = a.bsrc[i >> 10][i & 1023];
        return;
    }
    bx -= 20;
    {                                      // ---- feat x2
        const float* pc;  const float* W;  const float* bias;  unsigned short* out;
        if (bx < 8192) { pc = a.pitch_pc; W = a.Wc; bias = a.bc; out = a.cfb; }
        else { bx -= 8192; pc = a.bass_pc; W = a.Wb; bias = a.bb; out = a.bfb; }
        int idx = bx * 256 + tid;
        int s = idx >> 10, c = idx & 1023;
        float acc = bias[c];
#pragma unroll
        for (int i = 0; i < 12; ++i)
            acc = fmaf(pc[s * 12 + i], W[i * 1024 + c], acc);
        out[idx] = f2bf(acc);
    }
}

// ---------------------------------------------------------------- MFMA GEMM
// C[M x N] = A[M x 1024] @ Bt^T + bias.  BK=32, double-buffered, one barrier
// per K-tile. Per buffer: A 128x32 bf16 (8 KB) @0, B @8192. Row = 4 chunks of
// 16 B; chunk at pos p holds source chunk p ^ ((row>>1)&3).
// MODE 0: N=5120; wsel 0..2 scaled by QSCALE_, wsel 3 plain, wsel 4 -> Vt^T.
// MODE 1: N=1024, fp32 out.
template<int MODE>
__global__ __launch_bounds__(256) void gemm_k(
    const unsigned short* __restrict__ A, const unsigned short* __restrict__ Bt,
    const float* __restrict__ bias, unsigned short* __restrict__ Cb,
    unsigned short* __restrict__ Vt, float* __restrict__ Cf)
{
    __shared__ __align__(16) unsigned char lds[32768];   // buf0@0, buf1@16384
    const int tid = threadIdx.x;
    const int wv = tid >> 6, lane = tid & 63;
    const int lq = lane & 15, quad = lane >> 4;
    const int wm = wv >> 1, wn = wv & 1;
    const int m0 = blockIdx.y * 128, n0 = blockIdx.x * 128;

    const int sr = lane >> 2;
    const int sc = (lane & 3) ^ ((lane >> 3) & 3);
    const unsigned short* Abase = A + (size_t)m0 * 1024 + sc * 8;
    const unsigned short* Bbase = Bt + (size_t)n0 * 1024 + sc * 8;

    f32x4 acc[4][4] = {};

    // prologue: stage tile 0 -> buf0
#pragma unroll
    for (int j = 0; j < 2; ++j) {
        int seg = wv * 2 + j;
        GLDS16(Abase + (size_t)(seg * 16 + sr) * 1024, lds + seg * 1024);
        GLDS16(Bbase + (size_t)(seg * 16 + sr) * 1024, lds + 8192 + seg * 1024);
    }

    for (int kt = 0; kt < 32; ++kt) {
        __syncthreads();   // stage(kt) drained; all waves done compute(kt-1)
        unsigned char* cur = lds + (kt & 1) * 16384;

        if (kt + 1 < 32) {   // stage(kt+1) -> other buf (overlaps compute)
            const int k0n = (kt + 1) * 32;
            unsigned char* dst = lds + ((kt + 1) & 1) * 16384;
#pragma unroll
            for (int j = 0; j < 2; ++j) {
                int seg = wv * 2 + j;
                GLDS16(Abase + (size_t)(seg * 16 + sr) * 1024 + k0n, dst + seg * 1024);
                GLDS16(Bbase + (size_t)(seg * 16 + sr) * 1024 + k0n, dst + 8192 + seg * 1024);
            }
        }

        s16x8 aF[4], bF[4];
#pragma unroll
        for (int mi = 0; mi < 4; ++mi) {
            int row = wm * 64 + mi * 16 + lq;
            aF[mi] = *(const s16x8*)(cur + row * 64 + ((quad ^ ((row >> 1) & 3)) * 16));
        }
#pragma unroll
        for (int ni = 0; ni < 4; ++ni) {
            int row = wn * 64 + ni * 16 + lq;
            bF[ni] = *(const s16x8*)(cur + 8192 + row * 64 + ((quad ^ ((row >> 1) & 3)) * 16));
        }
#pragma unroll
        for (int mi = 0; mi < 4; ++mi)
#pragma unroll
            for (int ni = 0; ni < 4; ++ni)
                acc[mi][ni] = __builtin_amdgcn_mfma_f32_16x16x32_bf16(
                    aF[mi], bF[ni], acc[mi][ni], 0, 0, 0);
    }

    if (MODE == 0) {
        const int wsel = n0 >> 10;
        const float sc2 = (wsel <= 2) ? QSCALE_ : 1.0f;
#pragma unroll
        for (int ni = 0; ni < 4; ++ni) {
            int n = n0 + wn * 64 + ni * 16 + lq;
            float bv = bias[n];
            if (wsel == 4) {
                int nl = n - 4096, h = nl >> 6, d = nl & 63;
#pragma unroll
                for (int mi = 0; mi < 4; ++mi) {
                    int mrow = m0 + wm * 64 + mi * 16 + quad * 4;
                    uint2 w = {pk2(acc[mi][ni][0] + bv, acc[mi][ni][1] + bv),
                               pk2(acc[mi][ni][2] + bv, acc[mi][ni][3] + bv)};
                    *(uint2*)(Vt + ((size_t)h * 64 + d) * (size_t)M_ + mrow) = w;
                }
            } else {
#pragma unroll
                for (int mi = 0; mi < 4; ++mi) {
                    int mrow = m0 + wm * 64 + mi * 16 + quad * 4;
#pragma unroll
                    for (int r = 0; r < 4; ++r)
                        Cb[(size_t)(mrow + r) * NCAT_ + n] = f2bf((acc[mi][ni][r] + bv) * sc2);
                }
            }
        }
    } else {
#pragma unroll
        for (int ni = 0; ni < 4; ++ni) {
            int n = n0 + wn * 64 + ni * 16 + lq;
            float bv = bias[n];
#pragma unroll
            for (int mi = 0; mi < 4; ++mi) {
                int mrow = m0 + wm * 64 + mi * 16 + quad * 4;
#pragma unroll
                for (int r = 0; r < 4; ++r)
                    Cf[(size_t)(mrow + r) * 1024 + n] = acc[mi][ni][r] + bv;
            }
        }
    }
}

// ---------------------------------------------------------------- attention
// Block: one (b,h), 64 queries, 256 thr (4 waves x 16 q). 64 K-tiles of 32.
// LDS (36864 B): buf0@0, buf1@16384; per buf: K seg s @ s*4096 ([32k][128B],
// chunk c at pos c^(key&7)), V @ 12288 ([64d][64B], chunk c at pos
// c^((d>>1)&3)). P @ 32768: [64q][64B], chunk c at pos c^((q>>1)&3).
// Staging per kt: wave 0 -> K seg0 (Q5b+3072), 1 -> chord, 2 -> bass,
// 3 -> V; 4 parts x 1KB each, LDS dst = buf + wv*4096 + i*1024 (linear).
// Q direct global->VGPR (6x16B per lane, one-time).
// 4 blocks/CU (144KB LDS) = 4 independent barrier domains overlap each
// other's serial softmax/barrier phases; grid 1024 = exactly 256 CU x 4.
#define ATQ_ 64
#define KVB_ 32

__global__ __launch_bounds__(256, 4) void attn_kernel(
    const unsigned short* __restrict__ Q5b, const unsigned short* __restrict__ cfb,
    const unsigned short* __restrict__ bfb, const unsigned short* __restrict__ Vtg,
    unsigned short* __restrict__ ctxb)
{
    extern __shared__ __align__(16) unsigned char smem[];
    const int tid = threadIdx.x;
    const int wv = tid >> 6, lane = tid & 63;   // wv 0..3
    const int lq = lane & 15, quad = lane >> 4;
    const int bh = blockIdx.x;
    const int b = bh >> 4, h = bh & 15;
    const int q0 = blockIdx.y * ATQ_;
    const int lr = lane >> 3;                   // K-staging row-in-part
    const int g = (lane & 7) ^ lr;              // K-staging source chunk
    const int vrow = lane >> 2;                 // V-staging row-in-part
    const int vg = (lane & 3) ^ ((vrow >> 1) & 3);  // V-staging source chunk

    // ---- per-wave staging source (one buffer per wave)
    const unsigned short* sp;
    unsigned inc, pstep;
    if (wv == 0) {          // K keys: Q5b Kcat block
        sp = Q5b + (size_t)(b * S_ + lr) * NCAT_ + 3072 + h * 64 + g * 8;
        inc = KVB_ * NCAT_;  pstep = 8 * NCAT_;
    } else if (wv == 1) {   // chord_f
        sp = cfb + (size_t)lr * 1024 + h * 64 + g * 8;
        inc = KVB_ * 1024;   pstep = 8 * 1024;
    } else if (wv == 2) {   // bass_f
        sp = bfb + (size_t)lr * 1024 + h * 64 + g * 8;
        inc = KVB_ * 1024;   pstep = 8 * 1024;
    } else {                // V^T rows d
        sp = Vtg + (size_t)(h * 64 + vrow) * (size_t)M_ + b * S_ + vg * 8;
        inc = KVB_;          pstep = 16 * M_;
    }
    inc = __builtin_amdgcn_readfirstlane(inc);
    pstep = __builtin_amdgcn_readfirstlane(pstep);
    const unsigned lofs0 = wv * 4096;

    // ---- Q direct global->VGPR: qf[ds] = 16B at d-slice ds, query row
    s16x8 qf[6];
    {
        const unsigned short* qp = Q5b + (size_t)(b * S_ + q0 + wv * 16 + lq) * NCAT_
                                   + h * 64 + quad * 8;
#pragma unroll
        for (int ds = 0; ds < 6; ++ds)
            qf[ds] = *(const s16x8*)(qp + (ds >> 1) * 1024 + (ds & 1) * 32);
    }

    f32x4 o[4] = {};
    float lpart = 0.f;
    unsigned char* Pb = smem + 32768;

    // ---- prologue: stage tile 0 -> buf0
#pragma unroll
    for (int i = 0; i < 4; ++i)
        GLDS16(sp + (size_t)i * pstep, smem + lofs0 + i * 1024);
    sp += inc;

    for (int kt = 0; kt < 64; ++kt) {
        __syncthreads();   // stage(kt) drained; all waves past compute(kt-1)
        unsigned char* cur = smem + (kt & 1) * 16384;

        if (kt + 1 < 64) {   // stage(kt+1) -> other buf (overlaps compute)
            unsigned char* dst = smem + ((kt + 1) & 1) * 16384;
#pragma unroll
            for (int i = 0; i < 4; ++i)
                GLDS16(sp + (size_t)i * pstep, dst + lofs0 + i * 1024);
            sp += inc;
        }

        // ---- scores S^T = K * Q^T (A=K frag, B=Q frag); q = wv*16+lq
        f32x4 st[2] = {};
#pragma unroll
        for (int ka = 0; ka < 2; ++ka) {
            int key = ka * 16 + lq;
            __builtin_amdgcn_s_setprio(1);
#pragma unroll
            for (int ds = 0; ds < 6; ++ds) {
                int pos = ((ds & 1) * 4 + quad) ^ (key & 7);
                s16x8 kf = *(const s16x8*)(cur + (ds >> 1) * 4096 + key * 128 + pos * 16);
                st[ka] = __builtin_amdgcn_mfma_f32_16x16x32_bf16(
                    kf, qf[ds], st[ka], 0, 0, 0);
            }
            __builtin_amdgcn_s_setprio(0);
        }

        // ---- fixed-max softmax; P[q][k] bf16 via packed cvt
#pragma unroll
        for (int ka = 0; ka < 2; ++ka) {
            float p0 = EXP2(st[ka][0]);
            float p1 = EXP2(st[ka][1]);
            float p2 = EXP2(st[ka][2]);
            float p3 = EXP2(st[ka][3]);
            lpart += (p0 + p1) + (p2 + p3);
            int q = wv * 16 + lq;
            int c = ka * 2 + (quad >> 1);
            unsigned char* pp = Pb + q * 64 + ((c ^ ((q >> 1) & 3)) * 16) + (quad & 1) * 8;
            uint2 w = {pk2(p0, p1), pk2(p2, p3)};
            *(uint2*)pp = w;
        }

        // ---- PV: O += P @ V (A=P from LDS, B=V^T rows d)
        {
            int q = wv * 16 + lq;
            int ppos = quad ^ ((q >> 1) & 3);
            s16x8 pA = *(const s16x8*)(Pb + q * 64 + ppos * 16);
            __builtin_amdgcn_s_setprio(1);
#pragma unroll
            for (int ni = 0; ni < 4; ++ni) {
                int d = ni * 16 + lq;
                int pos = quad ^ ((d >> 1) & 3);
                s16x8 vB = *(const s16x8*)(cur + 12288 + d * 64 + pos * 16);
                o[ni] = __builtin_amdgcn_mfma_f32_16x16x32_bf16(pA, vB, o[ni], 0, 0, 0);
            }
            __builtin_amdgcn_s_setprio(0);
        }
    }

    // ---- epilogue: l is lq-indexed (q=wv*16+lq); O rows are quad*4+r
    {
        float l = lpart;
        l += __shfl_xor(l, 16);
        l += __shfl_xor(l, 32);
        float inv = 1.0f / l;
        float invr[4];
#pragma unroll
        for (int r = 0; r < 4; ++r)
            invr[r] = __shfl(inv, quad * 4 + r);
#pragma unroll
        for (int r = 0; r < 4; ++r) {
            int row = q0 + wv * 16 + quad * 4 + r;
#pragma unroll
            for (int ni = 0; ni < 4; ++ni)
                ctxb[(size_t)(b * S_ + row) * 1024 + h * 64 + ni * 16 + lq] =
                    f2bf(o[ni][r] * invr[r]);
        }
    }
}

// ---------------------------------------------------------------- launch
extern "C" void kernel_launch(void* const* d_in, const int* in_sizes, int n_in,
                              void* d_out, int out_size, void* d_ws, size_t ws_size,
                              hipStream_t stream)
{
    const float* x        = (const float*)d_in[0];
    const float* pitch_pc = (const float*)d_in[1];
    const float* bass_pc  = (const float*)d_in[2];
    const float* Wpq = (const float*)d_in[3];   const float* bpq = (const float*)d_in[4];
    const float* Whq = (const float*)d_in[5];   const float* bhq = (const float*)d_in[6];
    const float* Wvq = (const float*)d_in[7];   const float* bvq = (const float*)d_in[8];
    const float* Wk  = (const float*)d_in[9];   const float* bk  = (const float*)d_in[10];
    const float* Wv  = (const float*)d_in[11];  const float* bv  = (const float*)d_in[12];
    const float* Wo  = (const float*)d_in[13];  const float* bo  = (const float*)d_in[14];
    const float* Wc  = (const float*)d_in[15];  const float* bc  = (const float*)d_in[16];
    const float* Wb  = (const float*)d_in[17];  const float* bb  = (const float*)d_in[18];

    char* ws = (char*)d_ws;
    unsigned short* xb   = (unsigned short*)(ws);                      // 8 MB
    unsigned short* W5t  = (unsigned short*)(ws + 8388608);            // 10 MB
    unsigned short* Wot  = (unsigned short*)(ws + 18874368);           // 2 MB
    float*          bias5= (float*)         (ws + 20971520);           // 20 KB
    unsigned short* cfb  = (unsigned short*)(ws + 20992000);           // 4 MB
    unsigned short* bfb  = (unsigned short*)(ws + 25186304);           // 4 MB
    unsigned short* Q5b  = (unsigned short*)(ws + 29380608);           // 40 MB
    unsigned short* Vtg  = (unsigned short*)(ws + 71323648);           // 8 MB
    unsigned short* ctxb = (unsigned short*)(ws + 79712256);           // 8 MB

    PrepArgs pa;
    pa.x = x; pa.pitch_pc = pitch_pc; pa.bass_pc = bass_pc;
    pa.Wc = Wc; pa.bc = bc; pa.Wb = Wb; pa.bb = bb;
    pa.wsrc[0] = Wpq; pa.wsrc[1] = Whq; pa.wsrc[2] = Wvq;
    pa.wsrc[3] = Wk;  pa.wsrc[4] = Wv;  pa.wsrc[5] = Wv;
    pa.wsrc[4] = Wv;  pa.wsrc[5] = Wo;
    for (int i = 0; i < 5; ++i) pa.wdst[i] = W5t + (size_t)i * 1024 * 1024;
    pa.wdst[5] = Wot;
    pa.bsrc[0] = bpq; pa.bsrc[1] = bhq; pa.bsrc[2] = bvq; pa.bsrc[3] = bk; pa.bsrc[4] = bv;
    pa.bias5 = bias5; pa.xb = xb; pa.cfb = cfb; pa.bfb = bfb;

    prep_kernel<<<dim3(4096 + 1536 + 20 + 8192 + 8192), 256, 0, stream>>>(pa);

    gemm_k<0><<<dim3(40, 32), 256, 0, stream>>>(xb, W5t, bias5, Q5b, Vtg, nullptr);

    attn_kernel<<<dim3(B_ * H_, S_ / ATQ_), 256, 36864, stream>>>(Q5b, cfb, bfb, Vtg, ctxb);

    gemm_k<1><<<dim3(8, 32), 256, 0, stream>>>(ctxb, Wot, bo, nullptr, nullptr, (float*)d_out);
}